// Round 7
// baseline (1016.268 us; speedup 1.0000x reference)
//
#include <hip/hip_runtime.h>

// Problem constants (match reference setup_inputs)
constexpr int L = 64;
constexpr int P = 32768;          // nodes per level (2^15)
constexpr int N = L * P;          // 2,097,152 nodes
constexpr int E_PER = 262144;     // edges per group
constexpr int NLEVELS = L - 1;    // 63 groups; group g: src < (g+1)P, dst in level g+1

constexpr int NBLOCKS = 1024;     // 4 blocks/CU, cooperative co-resident
constexpr int NTHREADS = 256;     // 262144 threads = 1 edge/thread/group

// ws: per-block PRIVATE 64B lines (1 writer + 1 reader per line, no hot lines)
constexpr int ARR_OFF = 0;
constexpr int REL_OFF = NBLOCKS * 16;
constexpr int WS_INTS = 2 * NBLOCKS * 16;  // 128 KB

// LLC-direct (relaxed agent) ops: coherent at the memory-side Infinity Cache,
// bypass per-XCD L2, NO invalidates, NO fences. Protocol proven R5/R6 (absmax 0).
__device__ __forceinline__ int llc_ld(const int* p) {
    return __hip_atomic_load(p, __ATOMIC_RELAXED, __HIP_MEMORY_SCOPE_AGENT);
}
__device__ __forceinline__ void llc_st(int* p, int v) {
    __hip_atomic_store(p, v, __ATOMIC_RELAXED, __HIP_MEMORY_SCOPE_AGENT);
}
__device__ __forceinline__ float llc_ld_f(const float* p) {
    return __hip_atomic_load(p, __ATOMIC_RELAXED, __HIP_MEMORY_SCOPE_AGENT);
}

// R6's proven barrier (sleep quantum 2 -> 1). __syncthreads at arrival emits
// s_waitcnt vmcnt(0): every atomic this block issued (including pre-barrier
// slack work) is ACKed at the LLC before the arrival flag lands.
__device__ __forceinline__ void grid_barrier(int gen, int* arrive, int* release) {
    __syncthreads();                                   // drain vmem
    if (blockIdx.x == 0) {
        for (int b = 1 + (int)threadIdx.x; b < NBLOCKS; b += NTHREADS)
            while (llc_ld(&arrive[b * 16]) < gen)      // 4 private lines/thread
                __builtin_amdgcn_s_sleep(1);
        __syncthreads();                               // all arrivals verified
        for (int b = (int)threadIdx.x; b < NBLOCKS; b += NTHREADS)
            llc_st(&release[b * 16], gen);             // private line per block
        __syncthreads();
    } else {
        if (threadIdx.x == 0) {
            llc_st(&arrive[blockIdx.x * 16], gen);
            while (llc_ld(&release[blockIdx.x * 16]) < gen)
                __builtin_amdgcn_s_sleep(1);
        }
        __syncthreads();
    }
    asm volatile("" ::: "memory");                     // no compiler motion
}

// one edge: gather (LLC-direct, always fresh) + scatter-max (h>=0 -> uint
// bitpattern atomicMax == float max, executes at LLC, cross-XCD correct)
__device__ __forceinline__ void process_edge(float* out, int s, int d) {
    const float v = llc_ld_f(&out[s]) + 1.0f;
    atomicMax((unsigned int*)out + d, __float_as_uint(v));
}

// Slack schedule. Invariant at iter-e entry: levels <= e sealed & visible.
//   P1 (post-barrier): process held edges with s < (e+1)P  [small hot set]
//   P2 (pre-barrier):  load group e+2; if s < (e+1)P process NOW (its write
//       targets level e+3, first read two barriers later; its atomic drains
//       at THIS iter's barrier arrival) else hold.
//   barrier (gen e+2) seals level e+1: group e fully processed by end of
//       P1@e (P2@e-2 did s<(e-1)P, P1@e-1 did s<eP, P1@e did the rest).
__global__ void __launch_bounds__(NTHREADS)
pathfinder_kernel(const float* __restrict__ hdr,
                  const int* __restrict__ src,
                  const int* __restrict__ dst,
                  float* __restrict__ out,
                  int* __restrict__ ws) {
    const int tid = blockIdx.x * NTHREADS + threadIdx.x;   // 0..262143
    int* arrive  = ws + ARR_OFF;
    int* release = ws + REL_OFF;

    // ---- init: out = hdr (float4 x2/thread), flush to LLC once ----
    {
        const float4* h4 = (const float4*)hdr;
        float4* o4 = (float4*)out;
        o4[tid]         = h4[tid];
        o4[tid + E_PER] = h4[tid + E_PER];
    }
    __builtin_amdgcn_fence(__ATOMIC_RELEASE, "agent");

    // bootstrap: hold groups 0 and 1 (normal cached loads, immutable data)
    int sa = src[tid],          da = dst[tid];            // group 0
    int sb = src[E_PER + tid],  db = dst[E_PER + tid];    // group 1
    bool va = true, vb = true;

    grid_barrier(1, arrive, release);                     // level 0 sealed

    for (int e = 0; e < NLEVELS; ++e) {
        const int lim = (e + 1) * P;                      // s < lim => sealed

        // ---- P1: newly-unblocked held edges (small) ----
        if (va && sa < lim) { process_edge(out, sa, da); va = false; }
        if (vb && sb < lim) { process_edge(out, sb, db); vb = false; }

        // shift: held_a <- held_b remainder (group e+1, s in level e+1)
        sa = sb; da = db; va = vb;
        vb = false;

        // ---- P2: load group e+2; slack edges issue BEFORE the barrier ----
        if (e + 2 < NLEVELS) {
            const size_t off = (size_t)(e + 2) * E_PER + tid;
            const int s2 = src[off];
            const int d2 = dst[off];
            if (s2 < lim) {
                process_edge(out, s2, d2);                // drains at arrival
            } else {
                sb = s2; db = d2; vb = true;              // hot: defer
            }
        }

        // ---- barrier seals level e+1 (skip after final group) ----
        if (e < NLEVELS - 1) grid_barrier(e + 2, arrive, release);
    }
}

// ---- fallback (ws too small): R2's proven multi-launch version ----
__global__ void __launch_bounds__(256)
init_kernel(const float4* __restrict__ hdr, float4* __restrict__ out) {
    const int i = blockIdx.x * blockDim.x + threadIdx.x;
    out[i] = hdr[i];
}
__global__ void __launch_bounds__(256)
level_kernel(const int* __restrict__ s, const int* __restrict__ d,
             float* __restrict__ out) {
    const int e = blockIdx.x * blockDim.x + threadIdx.x;
    const float v = out[s[e]] + 1.0f;
    atomicMax((unsigned int*)out + d[e], __float_as_uint(v));
}

extern "C" void kernel_launch(void* const* d_in, const int* in_sizes, int n_in,
                              void* d_out, int out_size, void* d_ws, size_t ws_size,
                              hipStream_t stream) {
    const float* hdr = (const float*)d_in[0];
    const int*   src = (const int*)d_in[1];
    const int*   dst = (const int*)d_in[2];
    float*       out = (float*)d_out;
    int*         ws  = (int*)d_ws;

    if (ws_size >= WS_INTS * sizeof(int)) {
        void* args[] = {(void*)&hdr, (void*)&src, (void*)&dst,
                        (void*)&out, (void*)&ws};
        hipLaunchCooperativeKernel((void*)pathfinder_kernel,
                                   dim3(NBLOCKS), dim3(NTHREADS), args, 0, stream);
    } else {
        init_kernel<<<dim3(N / 4 / 256), dim3(256), 0, stream>>>(
            (const float4*)hdr, (float4*)out);
        for (int l = 0; l < NLEVELS; ++l)
            level_kernel<<<dim3(E_PER / 256), dim3(256), 0, stream>>>(
                src + (size_t)l * E_PER, dst + (size_t)l * E_PER, out);
    }
}